// Round 15
// baseline (1159.773 us; speedup 1.0000x reference)
//
#include <hip/hip_runtime.h>
#include <hip/hip_bf16.h>

#define WIDTH 1024
#define BATCH 8192

typedef __attribute__((ext_vector_type(8))) short short8;
typedef __attribute__((ext_vector_type(4))) float floatx4;

typedef __attribute__((address_space(1))) void gvoid;
typedef __attribute__((address_space(3))) void lvoid;

__device__ __forceinline__ void async_copy16(const void* g, void* l) {
    __builtin_amdgcn_global_load_lds((gvoid*)g, (lvoid*)l, 16, 0, 0);
}

__device__ __forceinline__ void split_store(float v, __hip_bfloat16* hi, __hip_bfloat16* lo, long idx) {
    __hip_bfloat16 h = __float2bfloat16(v);
    hi[idx] = h;
    lo[idx] = __float2bfloat16(v - __bfloat162float(h));
}

// ---------------- transpose W_h (fp32) -> Wt_hi/lo[n][k] bf16 ----------------
__global__ __launch_bounds__(256) void transpose_k(
    const float* __restrict__ W,
    __hip_bfloat16* __restrict__ Wth, __hip_bfloat16* __restrict__ Wtl)
{
    __shared__ float t[32][33];
    const int tx = threadIdx.x & 31, ty = threadIdx.x >> 5;
    const int bx = blockIdx.x << 5, by = blockIdx.y << 5;
#pragma unroll
    for (int r = 0; r < 32; r += 8)
        t[ty + r][tx] = W[(long)(by + ty + r) * WIDTH + bx + tx];
    __syncthreads();
#pragma unroll
    for (int r = 0; r < 32; r += 8)
        split_store(t[tx][ty + r], Wth, Wtl, (long)(bx + ty + r) * WIDTH + by + tx);
}

// ---------------- pack head weights: Wcat[32][1024] hi/lo ----------------
__global__ __launch_bounds__(256) void buildwcat_k(
    const float* __restrict__ W_ld, const float* __restrict__ W_lo,
    const float* __restrict__ W_g,
    __hip_bfloat16* __restrict__ Wch, __hip_bfloat16* __restrict__ Wcl)
{
    const int idx = blockIdx.x * 256 + threadIdx.x;   // 32*1024
    const int n = idx >> 10, k = idx & 1023;
    float v = 0.f;
    if (n < 7)       v = W_ld[k * 7 + n];
    else if (n < 28) v = W_lo[k * 21 + (n - 7)];
    else if (n == 28) v = W_g[k];
    split_store(v, Wch, Wcl, idx);
}

// ---------------- layer 1: Y1 split, D1 hi-only ----------------
__global__ __launch_bounds__(256) void prep_k(
    const float* __restrict__ state,
    const float* __restrict__ W_in,
    const float* __restrict__ b_in,
    __hip_bfloat16* __restrict__ Y1h, __hip_bfloat16* __restrict__ Y1l,
    __hip_bfloat16* __restrict__ D1h)
{
    const int b = blockIdx.x;
    const int j0 = threadIdx.x * 4;
    float s[7];
#pragma unroll
    for (int d = 0; d < 7; ++d) s[d] = state[b * 7 + d];
    float a[4];
#pragma unroll
    for (int q = 0; q < 4; ++q) a[q] = b_in[j0 + q];
    float w[7][4];
#pragma unroll
    for (int d = 0; d < 7; ++d)
#pragma unroll
        for (int q = 0; q < 4; ++q) {
            w[d][q] = W_in[d * WIDTH + j0 + q];
            a[q] += s[d] * w[d][q];
        }
    bool gp[4];
#pragma unroll
    for (int q = 0; q < 4; ++q) {
        gp[q] = a[q] > 0.f;
        split_store(gp[q] ? a[q] : 0.f, Y1h, Y1l, (long)b * WIDTH + j0 + q);
    }
    union { unsigned long long u64; unsigned short h[4]; } pk;
#pragma unroll
    for (int d = 0; d < 7; ++d) {
#pragma unroll
        for (int q = 0; q < 4; ++q) {
            __hip_bfloat16 v = __float2bfloat16(gp[q] ? w[d][q] : 0.f);
            pk.h[q] = *reinterpret_cast<unsigned short*>(&v);
        }
        *reinterpret_cast<unsigned long long*>(&D1h[((long)b * 7 + d) * WIDTH + j0]) = pk.u64;
    }
}

// ---------------- Y-GEMM body (3-pass split, relu+bias, split out) ----------------
__device__ __forceinline__ void y_gemm_body(
    short* SM,   // 16384 shorts
    int bm, int bn, int tid,
    const __hip_bfloat16* Ah, const __hip_bfloat16* Al,
    const __hip_bfloat16* Bh, const __hip_bfloat16* Bl,
    const float* bias,
    __hip_bfloat16* outh, __hip_bfloat16* outl)
{
    short* Ash = SM;          short* Asl = SM + 4096;
    short* Bsh = SM + 8192;   short* Bsl = SM + 12288;
    const int lane = tid & 63;
    const int wv = tid >> 6;
    const int wm = wv >> 1, wn = wv & 1;
    const int srow = tid >> 2;
    const int scol = (tid & 3) << 3;
    const short* pAh = (const short*)Ah + (long)(bm * 128 + srow) * WIDTH + scol;
    const short* pAl = (const short*)Al + (long)(bm * 128 + srow) * WIDTH + scol;
    const short* pBh = (const short*)Bh + (long)(bn * 128 + srow) * WIDTH + scol;
    const short* pBl = (const short*)Bl + (long)(bn * 128 + srow) * WIDTH + scol;
    const long half = 64l * WIDTH;

    floatx4 acc[4][4] = {};
    const int r = lane & 15;
    const int kq = (lane >> 4) << 3;

    for (int kt = 0; kt < WIDTH; kt += 32) {
        __syncthreads();
        async_copy16(pAh + kt,        Ash + wv * 512);
        async_copy16(pAh + half + kt, Ash + 2048 + wv * 512);
        async_copy16(pAl + kt,        Asl + wv * 512);
        async_copy16(pAl + half + kt, Asl + 2048 + wv * 512);
        async_copy16(pBh + kt,        Bsh + wv * 512);
        async_copy16(pBh + half + kt, Bsh + 2048 + wv * 512);
        async_copy16(pBl + kt,        Bsl + wv * 512);
        async_copy16(pBl + half + kt, Bsl + 2048 + wv * 512);
        __syncthreads();
        short8 afh[4], afl[4], bfh[4], bfl[4];
#pragma unroll
        for (int i = 0; i < 4; ++i) {
            const int ar = (wm * 64 + i * 16 + r) * 32 + kq;
            afh[i] = *reinterpret_cast<const short8*>(&Ash[ar]);
            afl[i] = *reinterpret_cast<const short8*>(&Asl[ar]);
        }
#pragma unroll
        for (int j = 0; j < 4; ++j) {
            const int br = (wn * 64 + j * 16 + r) * 32 + kq;
            bfh[j] = *reinterpret_cast<const short8*>(&Bsh[br]);
            bfl[j] = *reinterpret_cast<const short8*>(&Bsl[br]);
        }
#pragma unroll
        for (int i = 0; i < 4; ++i)
#pragma unroll
            for (int j = 0; j < 4; ++j) {
                acc[i][j] = __builtin_amdgcn_mfma_f32_16x16x32_bf16(afh[i], bfh[j], acc[i][j], 0, 0, 0);
                acc[i][j] = __builtin_amdgcn_mfma_f32_16x16x32_bf16(afh[i], bfl[j], acc[i][j], 0, 0, 0);
                acc[i][j] = __builtin_amdgcn_mfma_f32_16x16x32_bf16(afl[i], bfh[j], acc[i][j], 0, 0, 0);
            }
    }

    const int r4 = (lane >> 4) << 2;
#pragma unroll
    for (int i = 0; i < 4; ++i)
#pragma unroll
        for (int j = 0; j < 4; ++j) {
            const int col = bn * 128 + wn * 64 + j * 16 + r;
#pragma unroll
            for (int rr = 0; rr < 4; ++rr) {
                const int row = bm * 128 + wm * 64 + i * 16 + r4 + rr;
                float v = acc[i][j][rr] + bias[col];
                v = v > 0.f ? v : 0.f;
                split_store(v, outh, outl, (long)row * WIDTH + col);
            }
        }
}

// ---------------- Y2 GEMM (standalone) ----------------
__global__ __launch_bounds__(256) void gemm_y(
    const __hip_bfloat16* __restrict__ Ah, const __hip_bfloat16* __restrict__ Al,
    const __hip_bfloat16* __restrict__ Bh, const __hip_bfloat16* __restrict__ Bl,
    const float* __restrict__ bias,
    __hip_bfloat16* __restrict__ outh, __hip_bfloat16* __restrict__ outl)
{
    __shared__ __align__(16) short SM[16384];
    y_gemm_body(SM, blockIdx.x, blockIdx.y, threadIdx.x, Ah, Al, Bh, Bl, bias, outh, outl);
}

// ---------------- fused D2 + Y3 launch ----------------
// blocks x<nd: D2 1-pass bf16, LDS-FREE direct-load K-loop (AITER pattern, no barriers);
// x>=nd: Y3 3-pass LDS body (bm=x-nd).
__global__ __launch_bounds__(256) void d2y3_k(
    const __hip_bfloat16* __restrict__ D1,
    const __hip_bfloat16* __restrict__ Wth, const __hip_bfloat16* __restrict__ Wtl,
    const __hip_bfloat16* __restrict__ Y2h, const __hip_bfloat16* __restrict__ Y2l,
    const float* __restrict__ bias,
    __hip_bfloat16* __restrict__ D2out,
    __hip_bfloat16* __restrict__ Y3h, __hip_bfloat16* __restrict__ Y3l,
    int nd)
{
    __shared__ __align__(16) short SM[16384];
    const int tid = threadIdx.x;
    if ((int)blockIdx.x >= nd) {
        y_gemm_body(SM, blockIdx.x - nd, blockIdx.y, tid, Y2h, Y2l, Wth, Wtl, bias, Y3h, Y3l);
        return;
    }
    // ---- D2 body: direct global->VGPR fragments, no LDS, no barriers ----
    const int lane = tid & 63;
    const int wv = tid >> 6;
    const int wm = wv >> 1, wn = wv & 1;
    const int bm = blockIdx.x, bn = blockIdx.y;
    const int r = lane & 15;
    const int kq = (lane >> 4) << 3;

    const short* A_ = (const short*)D1;
    const short* B_ = (const short*)Wth;
    long aoff[4], boff[4];
#pragma unroll
    for (int i = 0; i < 4; ++i)
        aoff[i] = (long)(bm * 128 + wm * 64 + i * 16 + r) * WIDTH + kq;
#pragma unroll
    for (int j = 0; j < 4; ++j)
        boff[j] = (long)(bn * 128 + wn * 64 + j * 16 + r) * WIDTH + kq;

    floatx4 acc[4][4] = {};
#pragma unroll 2
    for (int kt = 0; kt < WIDTH; kt += 32) {
        short8 a[4], b[4];
#pragma unroll
        for (int i = 0; i < 4; ++i)
            a[i] = *reinterpret_cast<const short8*>(A_ + aoff[i] + kt);
#pragma unroll
        for (int j = 0; j < 4; ++j)
            b[j] = *reinterpret_cast<const short8*>(B_ + boff[j] + kt);
#pragma unroll
        for (int i = 0; i < 4; ++i)
#pragma unroll
            for (int j = 0; j < 4; ++j)
                acc[i][j] = __builtin_amdgcn_mfma_f32_16x16x32_bf16(a[i], b[j], acc[i][j], 0, 0, 0);
    }

    const int r4 = (lane >> 4) << 2;
#pragma unroll
    for (int i = 0; i < 4; ++i)
#pragma unroll
        for (int j = 0; j < 4; ++j) {
            const int col = bn * 128 + wn * 64 + j * 16 + r;
#pragma unroll
            for (int rr = 0; rr < 4; ++rr) {
                const int row = bm * 128 + wm * 64 + i * 16 + r4 + rr;
                float v = acc[i][j][rr];
                const unsigned brow = (unsigned)row / 7u;
                if (!(__bfloat162float(Y2h[(long)brow * WIDTH + col]) > 0.f)) v = 0.f;
                D2out[(long)row * WIDTH + col] = __float2bfloat16(v);
            }
        }
}

// ---------------- fused D3(+PD projection) + heady launch ----------------
// blocks x<nd: D3 LDS-free direct-load K-loop + LDS projection epilogue;
// x>=nd && y==0: heady (Y3 projection, 3-pass); else idle.
__global__ __launch_bounds__(256) void d3heady_k(
    const __hip_bfloat16* __restrict__ D2,
    const __hip_bfloat16* __restrict__ Wth, const __hip_bfloat16* __restrict__ Wtl,
    const __hip_bfloat16* __restrict__ Y3h, const __hip_bfloat16* __restrict__ Y3l,
    const __hip_bfloat16* __restrict__ Wch, const __hip_bfloat16* __restrict__ Wcl,
    float* __restrict__ PDpart, float* __restrict__ PY,
    int nd, int Mrows)
{
    __shared__ __align__(16) short SM[26112];  // 52 KB
    const int tid = threadIdx.x;
    const int lane = tid & 63;
    const int wv = tid >> 6;
    const int r = lane & 15;
    const int kq = (lane >> 4) << 3;
    const int r4 = (lane >> 4) << 2;
    const int srow = tid >> 2;
    const int scol = (tid & 3) << 3;
    const long half = 64l * WIDTH;

    if ((int)blockIdx.x >= nd) {
        if (blockIdx.y != 0) return;
        // ---- heady body (3-pass Y3 @ Wcat^T) ----
        short* Ash = SM;          short* Asl = SM + 4096;
        short* Bsh = SM + 8192;   short* Bsl = SM + 9216;
        const int bm = blockIdx.x - nd;
        const short* pAh = (const short*)Y3h + (long)(bm * 128 + srow) * WIDTH + scol;
        const short* pAl = (const short*)Y3l + (long)(bm * 128 + srow) * WIDTH + scol;
        const long boff = (long)srow * WIDTH + scol;
        const short* pBh = (const short*)Wch;  const short* pBl = (const short*)Wcl;

        floatx4 acc[2][2] = {};
        for (int kt = 0; kt < WIDTH; kt += 32) {
            short8 gbh, gbl;
            if (tid < 128) {
                gbh = *reinterpret_cast<const short8*>(pBh + boff + kt);
                gbl = *reinterpret_cast<const short8*>(pBl + boff + kt);
            }
            __syncthreads();
            async_copy16(pAh + kt,        Ash + wv * 512);
            async_copy16(pAh + half + kt, Ash + 2048 + wv * 512);
            async_copy16(pAl + kt,        Asl + wv * 512);
            async_copy16(pAl + half + kt, Asl + 2048 + wv * 512);
            if (tid < 128) {
                *reinterpret_cast<short8*>(&Bsh[srow * 32 + scol]) = gbh;
                *reinterpret_cast<short8*>(&Bsl[srow * 32 + scol]) = gbl;
            }
            __syncthreads();
            short8 afh[2], afl[2], bfh[2], bfl[2];
#pragma unroll
            for (int i = 0; i < 2; ++i) {
                const int ar = (wv * 32 + i * 16 + r) * 32 + kq;
                afh[i] = *reinterpret_cast<const short8*>(&Ash[ar]);
                afl[i] = *reinterpret_cast<const short8*>(&Asl[ar]);
            }
#pragma unroll
            for (int j = 0; j < 2; ++j) {
                const int br = (j * 16 + r) * 32 + kq;
                bfh[j] = *reinterpret_cast<const short8*>(&Bsh[br]);
                bfl[j] = *reinterpret_cast<const short8*>(&Bsl[br]);
            }
#pragma unroll
            for (int i = 0; i < 2; ++i)
#pragma unroll
                for (int j = 0; j < 2; ++j) {
                    acc[i][j] = __builtin_amdgcn_mfma_f32_16x16x32_bf16(afh[i], bfh[j], acc[i][j], 0, 0, 0);
                    acc[i][j] = __builtin_amdgcn_mfma_f32_16x16x32_bf16(afh[i], bfl[j], acc[i][j], 0, 0, 0);
                    acc[i][j] = __builtin_amdgcn_mfma_f32_16x16x32_bf16(afl[i], bfh[j], acc[i][j], 0, 0, 0);
                }
        }
#pragma unroll
        for (int i = 0; i < 2; ++i)
#pragma unroll
            for (int j = 0; j < 2; ++j)
#pragma unroll
                for (int rr = 0; rr < 4; ++rr) {
                    const int row = bm * 128 + wv * 32 + i * 16 + r4 + rr;
                    PY[(long)row * 32 + j * 16 + r] = acc[i][j][rr];
                }
        return;
    }

    // ---- D3 body: direct global->VGPR fragments (no LDS in K-loop) + fused PD projection ----
    short* T    = SM;            // 128 x 136
    short* WcH  = SM + 17408;    // 32 x 136
    short* WcL  = SM + 21760;    // 32 x 136

    const int wm = wv >> 1, wn = wv & 1;
    const int bm = blockIdx.x, bn = blockIdx.y;
    const short* A_ = (const short*)D2;
    const short* B_ = (const short*)Wth;
    long aoff[4], boff2[4];
#pragma unroll
    for (int i = 0; i < 4; ++i)
        aoff[i] = (long)(bm * 128 + wm * 64 + i * 16 + r) * WIDTH + kq;
#pragma unroll
    for (int j = 0; j < 4; ++j)
        boff2[j] = (long)(bn * 128 + wn * 64 + j * 16 + r) * WIDTH + kq;

    floatx4 acc[4][4] = {};
#pragma unroll 2
    for (int kt = 0; kt < WIDTH; kt += 32) {
        short8 a[4], b[4];
#pragma unroll
        for (int i = 0; i < 4; ++i)
            a[i] = *reinterpret_cast<const short8*>(A_ + aoff[i] + kt);
#pragma unroll
        for (int j = 0; j < 4; ++j)
            b[j] = *reinterpret_cast<const short8*>(B_ + boff2[j] + kt);
#pragma unroll
        for (int i = 0; i < 4; ++i)
#pragma unroll
            for (int j = 0; j < 4; ++j)
                acc[i][j] = __builtin_amdgcn_mfma_f32_16x16x32_bf16(a[i], b[j], acc[i][j], 0, 0, 0);
    }

    // mask + write bf16 tile to LDS (D3 values never hit HBM)
#pragma unroll
    for (int i = 0; i < 4; ++i)
#pragma unroll
        for (int j = 0; j < 4; ++j) {
            const int coll = wn * 64 + j * 16 + r;
            const int colg = bn * 128 + coll;
#pragma unroll
            for (int rr = 0; rr < 4; ++rr) {
                const int rowl = wm * 64 + i * 16 + r4 + rr;
                const int rowg = bm * 128 + rowl;
                float v = acc[i][j][rr];
                const unsigned brow = (unsigned)rowg / 7u;
                if (!(__bfloat162float(Y3h[(long)brow * WIDTH + colg]) > 0.f)) v = 0.f;
                __hip_bfloat16 hb = __float2bfloat16(v);
                T[rowl * 136 + coll] = *reinterpret_cast<short*>(&hb);
            }
        }
    {
        const int n = tid >> 4, k8 = (tid & 15) * 8;
        const short* wh = (const short*)Wch;
        const short* wl = (const short*)Wcl;
        *reinterpret_cast<short8*>(&WcH[n * 136 + k8]) =
            *reinterpret_cast<const short8*>(wh + n * WIDTH + bn * 128 + k8);
        *reinterpret_cast<short8*>(&WcH[(n + 16) * 136 + k8]) =
            *reinterpret_cast<const short8*>(wh + (n + 16) * WIDTH + bn * 128 + k8);
        *reinterpret_cast<short8*>(&WcL[n * 136 + k8]) =
            *reinterpret_cast<const short8*>(wl + n * WIDTH + bn * 128 + k8);
        *reinterpret_cast<short8*>(&WcL[(n + 16) * 136 + k8]) =
            *reinterpret_cast<const short8*>(wl + (n + 16) * WIDTH + bn * 128 + k8);
    }
    __syncthreads();

    floatx4 accp[2][2] = {};
#pragma unroll
    for (int kk = 0; kk < 128; kk += 32) {
        short8 af[2], bh8[2], bl8[2];
#pragma unroll
        for (int i = 0; i < 2; ++i)
            af[i] = *reinterpret_cast<const short8*>(&T[(wv * 32 + i * 16 + r) * 136 + kk + kq]);
#pragma unroll
        for (int j = 0; j < 2; ++j) {
            bh8[j] = *reinterpret_cast<const short8*>(&WcH[(j * 16 + r) * 136 + kk + kq]);
            bl8[j] = *reinterpret_cast<const short8*>(&WcL[(j * 16 + r) * 136 + kk + kq]);
        }
#pragma unroll
        for (int i = 0; i < 2; ++i)
#pragma unroll
            for (int j = 0; j < 2; ++j) {
                accp[i][j] = __builtin_amdgcn_mfma_f32_16x16x32_bf16(af[i], bh8[j], accp[i][j], 0, 0, 0);
                accp[i][j] = __builtin_amdgcn_mfma_f32_16x16x32_bf16(af[i], bl8[j], accp[i][j], 0, 0, 0);
            }
    }
#pragma unroll
    for (int i = 0; i < 2; ++i)
#pragma unroll
        for (int j = 0; j < 2; ++j)
#pragma unroll
            for (int rr = 0; rr < 4; ++rr) {
                const int rowg = bm * 128 + wv * 32 + i * 16 + r4 + rr;
                PDpart[((long)bn * Mrows + rowg) * 32 + j * 16 + r] = accp[i][j][rr];
            }
}

// ---------------- finalize: 7x7 algebra; reduces PDpart inline ----------------
__device__ __forceinline__ int midx(int rr, int cc) {
    const int i = rr - cc;
    return i * 7 - (i * (i - 1)) / 2 + cc;
}

__global__ __launch_bounds__(64) void finalize_k(
    const float* __restrict__ PY,
    const float* __restrict__ PDpart,   // [8][Mrows][32]
    const float* __restrict__ vel_g,
    const float* __restrict__ acc_g,
    const float* __restrict__ b_ld,
    const float* __restrict__ b_lo,
    float* __restrict__ out,
    int b0, int Mrows)
{
    __shared__ float lval[28];
    __shared__ int gpv[7];
    __shared__ float derl[29 * 7];
    __shared__ float Lm[49], Mm[49], dLt[49], uu[49];
    __shared__ float wvv[7], pv[7], Cv[7], Gv[7], tauv[7], vl[7], ac[7];

    const int bl = blockIdx.x, tid = threadIdx.x;
    const int b = b0 + bl;
    if (tid < 28) {
        float s = PY[(long)bl * 32 + tid];
        if (tid < 7) {
            s += b_ld[tid];
            gpv[tid] = s > 0.f;
            lval[tid] = s > 0.f ? s : 0.f;
        } else {
            lval[tid] = s + b_lo[tid - 7];
        }
    }
    if (tid >= 28 && tid < 35) {
        vl[tid - 28] = vel_g[b * 7 + tid - 28];
        ac[tid - 28] = acc_g[b * 7 + tid - 28];
    }
    __syncthreads();
    for (int idx = tid; idx < 203; idx += 64) {
        const int m = idx / 7, d = idx % 7;
        float v = 0.f;
#pragma unroll
        for (int p = 0; p < 8; ++p)
            v += PDpart[((long)p * Mrows + bl * 7 + d) * 32 + m];
        if (m < 7 && !gpv[m]) v = 0.f;
        derl[m * 7 + d] = v;
    }
    __syncthreads();
    if (tid < 49) {
        const int rr = tid / 7, cc = tid % 7;
        Lm[tid] = (rr >= cc) ? lval[midx(rr, cc)] : 0.f;
    }
    __syncthreads();
    if (tid < 49) {
        const int rr = tid / 7, cc = tid % 7;
        float s = 0.f;
        for (int k = 0; k < 7; ++k) s += Lm[rr * 7 + k] * Lm[cc * 7 + k];
        if (rr == cc) s += 1e-5f;
        Mm[tid] = s;
        float t = 0.f;
        if (rr >= cc) {
            const int m = midx(rr, cc);
            for (int d = 0; d < 7; ++d) t += derl[m * 7 + d] * vl[d];
        }
        dLt[tid] = t;
        float u = 0.f;
        for (int r2 = cc; r2 < 7; ++r2) u += vl[r2] * derl[midx(r2, cc) * 7 + rr];
        uu[tid] = u;
    } else if (tid >= 49 && tid < 56) {
        const int j = tid - 49;
        float s = 0.f;
        for (int r2 = 0; r2 < 7; ++r2) s += Lm[r2 * 7 + j] * vl[r2];
        wvv[j] = s;
    }
    __syncthreads();
    if (tid < 7) {
        float s = 0.f;
        for (int r2 = 0; r2 < 7; ++r2) s += dLt[r2 * 7 + tid] * vl[r2];
        pv[tid] = s;
    }
    __syncthreads();
    if (tid < 7) {
        float s = 0.f, q = 0.f, md = 0.f;
        for (int c = 0; c < 7; ++c) {
            s += Lm[tid * 7 + c] * pv[c] + dLt[tid * 7 + c] * wvv[c];
            q += uu[tid * 7 + c] * wvv[c];
            md += Mm[tid * 7 + c] * ac[c];
        }
        Cv[tid] = s - q;
        Gv[tid] = derl[28 * 7 + tid];
        tauv[tid] = md + Cv[tid] + Gv[tid];
    }
    __syncthreads();
    if (tid < 49) out[57344 + (long)b * 49 + tid] = Mm[tid];
    if (tid < 7) {
        out[(long)b * 7 + tid] = tauv[tid];
        out[458752 + (long)b * 7 + tid] = Cv[tid];
        out[516096 + (long)b * 7 + tid] = Gv[tid];
    }
}

extern "C" void kernel_launch(void* const* d_in, const int* in_sizes, int n_in,
                              void* d_out, int out_size, void* d_ws, size_t ws_size,
                              hipStream_t stream)
{
    const float* state = (const float*)d_in[0];
    const float* vel   = (const float*)d_in[1];
    const float* accel = (const float*)d_in[2];
    const float* W_in  = (const float*)d_in[3];
    const float* b_in  = (const float*)d_in[4];
    const float* W_h   = (const float*)d_in[5];
    const float* b_h   = (const float*)d_in[6];
    const float* W_g   = (const float*)d_in[7];
    /* d_in[8] = b_g unused */
    const float* W_ld  = (const float*)d_in[9];
    const float* b_ld  = (const float*)d_in[10];
    const float* W_lo  = (const float*)d_in[11];
    const float* b_lo  = (const float*)d_in[12];
    float* outp = (float*)d_out;

    char* ws = (char*)d_ws;
    __hip_bfloat16* Wth = (__hip_bfloat16*)ws; ws += (size_t)WIDTH * WIDTH * 2;
    __hip_bfloat16* Wtl = (__hip_bfloat16*)ws; ws += (size_t)WIDTH * WIDTH * 2;
    __hip_bfloat16* Wch = (__hip_bfloat16*)ws; ws += 32 * WIDTH * 2;
    __hip_bfloat16* Wcl = (__hip_bfloat16*)ws; ws += 32 * WIDTH * 2;
    const size_t fixed = (size_t)(ws - (char*)d_ws);

    // per-sample: Y 4*2048 + D1 14336 + D2 14336 + PY 128 = 37120 B
    int CH = 128;
    for (int cand = 8192; cand >= 128; cand >>= 1) {
        size_t need = fixed + (size_t)cand * 37120;
        if (need <= ws_size) { CH = cand; break; }
    }
    const int NCH = BATCH / CH;

    const size_t YB = (size_t)CH * WIDTH * 2;
    const size_t DB = (size_t)CH * 7 * WIDTH * 2;
    __hip_bfloat16* Yah = (__hip_bfloat16*)ws; ws += YB;   // Y1 -> Y3
    __hip_bfloat16* Yal = (__hip_bfloat16*)ws; ws += YB;
    __hip_bfloat16* Ybh = (__hip_bfloat16*)ws; ws += YB;   // Y2
    __hip_bfloat16* Ybl = (__hip_bfloat16*)ws; ws += YB;
    __hip_bfloat16* Dah = (__hip_bfloat16*)ws; ws += DB;   // D1 (aliased as PDpart in D3 phase)
    __hip_bfloat16* Dbh = (__hip_bfloat16*)ws; ws += DB;   // D2
    float* PY = (float*)ws; ws += (size_t)CH * 32 * 4;
    float* PDpart = (float*)Dah;   // 8*(7*CH)*32*4 = CH*7168 B <= DB

    const int Mrows = CH * 7;
    const int nd = Mrows / 128;
    const int ny = CH / 128;

    transpose_k<<<dim3(32, 32), dim3(256), 0, stream>>>(W_h, Wth, Wtl);
    buildwcat_k<<<dim3(128), dim3(256), 0, stream>>>(W_ld, W_lo, W_g, Wch, Wcl);

    for (int c = 0; c < NCH; ++c) {
        prep_k<<<dim3(CH), dim3(256), 0, stream>>>(state + (size_t)c * CH * 7, W_in, b_in,
                                                   Yah, Yal, Dah);
        gemm_y<<<dim3(ny, 8), dim3(256), 0, stream>>>(
            Yah, Yal, Wth, Wtl, b_h, Ybh, Ybl);                                // Y2
        d2y3_k<<<dim3(nd + ny, 8), dim3(256), 0, stream>>>(
            Dah, Wth, Wtl, Ybh, Ybl, b_h, Dbh, Yah, Yal, nd);                  // D2 + Y3
        d3heady_k<<<dim3(nd + ny, 8), dim3(256), 0, stream>>>(
            Dbh, Wth, Wtl, Yah, Yal, Wch, Wcl, PDpart, PY, nd, Mrows);         // D3+PD + heady
        finalize_k<<<dim3(CH), dim3(64), 0, stream>>>(PY, PDpart, vel, accel, b_ld, b_lo,
                                                      outp, c * CH, Mrows);
    }
    (void)in_sizes; (void)n_in; (void)out_size;
}

// Round 16
// 666.426 us; speedup vs baseline: 1.7403x; 1.7403x over previous
//
#include <hip/hip_runtime.h>
#include <hip/hip_bf16.h>

#define WIDTH 1024
#define BATCH 8192

typedef __attribute__((ext_vector_type(8))) short short8;
typedef __attribute__((ext_vector_type(4))) float floatx4;

typedef __attribute__((address_space(1))) void gvoid;
typedef __attribute__((address_space(3))) void lvoid;

__device__ __forceinline__ void async_copy16(const void* g, void* l) {
    __builtin_amdgcn_global_load_lds((gvoid*)g, (lvoid*)l, 16, 0, 0);
}

__device__ __forceinline__ void split_store(float v, __hip_bfloat16* hi, __hip_bfloat16* lo, long idx) {
    __hip_bfloat16 h = __float2bfloat16(v);
    hi[idx] = h;
    lo[idx] = __float2bfloat16(v - __bfloat162float(h));
}

// ---------------- transpose W_h (fp32) -> Wt_hi/lo[n][k] bf16 ----------------
__global__ __launch_bounds__(256) void transpose_k(
    const float* __restrict__ W,
    __hip_bfloat16* __restrict__ Wth, __hip_bfloat16* __restrict__ Wtl)
{
    __shared__ float t[32][33];
    const int tx = threadIdx.x & 31, ty = threadIdx.x >> 5;
    const int bx = blockIdx.x << 5, by = blockIdx.y << 5;
#pragma unroll
    for (int r = 0; r < 32; r += 8)
        t[ty + r][tx] = W[(long)(by + ty + r) * WIDTH + bx + tx];
    __syncthreads();
#pragma unroll
    for (int r = 0; r < 32; r += 8)
        split_store(t[tx][ty + r], Wth, Wtl, (long)(bx + ty + r) * WIDTH + by + tx);
}

// ---------------- pack head weights: Wcat[32][1024] hi/lo ----------------
__global__ __launch_bounds__(256) void buildwcat_k(
    const float* __restrict__ W_ld, const float* __restrict__ W_lo,
    const float* __restrict__ W_g,
    __hip_bfloat16* __restrict__ Wch, __hip_bfloat16* __restrict__ Wcl)
{
    const int idx = blockIdx.x * 256 + threadIdx.x;   // 32*1024
    const int n = idx >> 10, k = idx & 1023;
    float v = 0.f;
    if (n < 7)       v = W_ld[k * 7 + n];
    else if (n < 28) v = W_lo[k * 21 + (n - 7)];
    else if (n == 28) v = W_g[k];
    split_store(v, Wch, Wcl, idx);
}

// ---------------- layer 1: Y1 split, D1 hi-only ----------------
__global__ __launch_bounds__(256) void prep_k(
    const float* __restrict__ state,
    const float* __restrict__ W_in,
    const float* __restrict__ b_in,
    __hip_bfloat16* __restrict__ Y1h, __hip_bfloat16* __restrict__ Y1l,
    __hip_bfloat16* __restrict__ D1h)
{
    const int b = blockIdx.x;
    const int j0 = threadIdx.x * 4;
    float s[7];
#pragma unroll
    for (int d = 0; d < 7; ++d) s[d] = state[b * 7 + d];
    float a[4];
#pragma unroll
    for (int q = 0; q < 4; ++q) a[q] = b_in[j0 + q];
    float w[7][4];
#pragma unroll
    for (int d = 0; d < 7; ++d)
#pragma unroll
        for (int q = 0; q < 4; ++q) {
            w[d][q] = W_in[d * WIDTH + j0 + q];
            a[q] += s[d] * w[d][q];
        }
    bool gp[4];
#pragma unroll
    for (int q = 0; q < 4; ++q) {
        gp[q] = a[q] > 0.f;
        split_store(gp[q] ? a[q] : 0.f, Y1h, Y1l, (long)b * WIDTH + j0 + q);
    }
    union { unsigned long long u64; unsigned short h[4]; } pk;
#pragma unroll
    for (int d = 0; d < 7; ++d) {
#pragma unroll
        for (int q = 0; q < 4; ++q) {
            __hip_bfloat16 v = __float2bfloat16(gp[q] ? w[d][q] : 0.f);
            pk.h[q] = *reinterpret_cast<unsigned short*>(&v);
        }
        *reinterpret_cast<unsigned long long*>(&D1h[((long)b * 7 + d) * WIDTH + j0]) = pk.u64;
    }
}

// ---------------- Y-GEMM body (3-pass split, relu+bias, split out) ----------------
__device__ __forceinline__ void y_gemm_body(
    short* SM,   // 16384 shorts
    int bm, int bn, int tid,
    const __hip_bfloat16* Ah, const __hip_bfloat16* Al,
    const __hip_bfloat16* Bh, const __hip_bfloat16* Bl,
    const float* bias,
    __hip_bfloat16* outh, __hip_bfloat16* outl)
{
    short* Ash = SM;          short* Asl = SM + 4096;
    short* Bsh = SM + 8192;   short* Bsl = SM + 12288;
    const int lane = tid & 63;
    const int wv = tid >> 6;
    const int wm = wv >> 1, wn = wv & 1;
    const int srow = tid >> 2;
    const int scol = (tid & 3) << 3;
    const short* pAh = (const short*)Ah + (long)(bm * 128 + srow) * WIDTH + scol;
    const short* pAl = (const short*)Al + (long)(bm * 128 + srow) * WIDTH + scol;
    const short* pBh = (const short*)Bh + (long)(bn * 128 + srow) * WIDTH + scol;
    const short* pBl = (const short*)Bl + (long)(bn * 128 + srow) * WIDTH + scol;
    const long half = 64l * WIDTH;

    floatx4 acc[4][4] = {};
    const int r = lane & 15;
    const int kq = (lane >> 4) << 3;

    for (int kt = 0; kt < WIDTH; kt += 32) {
        __syncthreads();
        async_copy16(pAh + kt,        Ash + wv * 512);
        async_copy16(pAh + half + kt, Ash + 2048 + wv * 512);
        async_copy16(pAl + kt,        Asl + wv * 512);
        async_copy16(pAl + half + kt, Asl + 2048 + wv * 512);
        async_copy16(pBh + kt,        Bsh + wv * 512);
        async_copy16(pBh + half + kt, Bsh + 2048 + wv * 512);
        async_copy16(pBl + kt,        Bsl + wv * 512);
        async_copy16(pBl + half + kt, Bsl + 2048 + wv * 512);
        __syncthreads();
        short8 afh[4], afl[4], bfh[4], bfl[4];
#pragma unroll
        for (int i = 0; i < 4; ++i) {
            const int ar = (wm * 64 + i * 16 + r) * 32 + kq;
            afh[i] = *reinterpret_cast<const short8*>(&Ash[ar]);
            afl[i] = *reinterpret_cast<const short8*>(&Asl[ar]);
        }
#pragma unroll
        for (int j = 0; j < 4; ++j) {
            const int br = (wn * 64 + j * 16 + r) * 32 + kq;
            bfh[j] = *reinterpret_cast<const short8*>(&Bsh[br]);
            bfl[j] = *reinterpret_cast<const short8*>(&Bsl[br]);
        }
#pragma unroll
        for (int i = 0; i < 4; ++i)
#pragma unroll
            for (int j = 0; j < 4; ++j) {
                acc[i][j] = __builtin_amdgcn_mfma_f32_16x16x32_bf16(afh[i], bfh[j], acc[i][j], 0, 0, 0);
                acc[i][j] = __builtin_amdgcn_mfma_f32_16x16x32_bf16(afh[i], bfl[j], acc[i][j], 0, 0, 0);
                acc[i][j] = __builtin_amdgcn_mfma_f32_16x16x32_bf16(afl[i], bfh[j], acc[i][j], 0, 0, 0);
            }
    }

    const int r4 = (lane >> 4) << 2;
#pragma unroll
    for (int i = 0; i < 4; ++i)
#pragma unroll
        for (int j = 0; j < 4; ++j) {
            const int col = bn * 128 + wn * 64 + j * 16 + r;
#pragma unroll
            for (int rr = 0; rr < 4; ++rr) {
                const int row = bm * 128 + wm * 64 + i * 16 + r4 + rr;
                float v = acc[i][j][rr] + bias[col];
                v = v > 0.f ? v : 0.f;
                split_store(v, outh, outl, (long)row * WIDTH + col);
            }
        }
}

// ---------------- Y2 GEMM (standalone) ----------------
__global__ __launch_bounds__(256) void gemm_y(
    const __hip_bfloat16* __restrict__ Ah, const __hip_bfloat16* __restrict__ Al,
    const __hip_bfloat16* __restrict__ Bh, const __hip_bfloat16* __restrict__ Bl,
    const float* __restrict__ bias,
    __hip_bfloat16* __restrict__ outh, __hip_bfloat16* __restrict__ outl)
{
    __shared__ __align__(16) short SM[16384];
    y_gemm_body(SM, blockIdx.x, blockIdx.y, threadIdx.x, Ah, Al, Bh, Bl, bias, outh, outl);
}

// ---------------- fused D2 + Y3 launch ----------------
// blocks x<nd: D2 1-pass bf16 BK=64 (bm=x fastest); x>=nd: Y3 3-pass (bm=x-nd).
__global__ __launch_bounds__(256) void d2y3_k(
    const __hip_bfloat16* __restrict__ D1,
    const __hip_bfloat16* __restrict__ Wth, const __hip_bfloat16* __restrict__ Wtl,
    const __hip_bfloat16* __restrict__ Y2h, const __hip_bfloat16* __restrict__ Y2l,
    const float* __restrict__ bias,
    __hip_bfloat16* __restrict__ D2out,
    __hip_bfloat16* __restrict__ Y3h, __hip_bfloat16* __restrict__ Y3l,
    int nd)
{
    __shared__ __align__(16) short SM[16384];
    const int tid = threadIdx.x;
    if ((int)blockIdx.x >= nd) {
        y_gemm_body(SM, blockIdx.x - nd, blockIdx.y, tid, Y2h, Y2l, Wth, Wtl, bias, Y3h, Y3l);
        return;
    }
    // ---- D2 body ----
    short* Ash0 = SM;         short* Ash1 = SM + 4096;
    short* Bsh0 = SM + 8192;  short* Bsh1 = SM + 12288;
    const int lane = tid & 63;
    const int wv = tid >> 6;
    const int wm = wv >> 1, wn = wv & 1;
    const int bm = blockIdx.x, bn = blockIdx.y;

    const int srow = tid >> 2;
    const int scol = (tid & 3) << 3;
    const short* pAh = (const short*)D1 + (long)(bm * 128 + srow) * WIDTH + scol;
    const short* pBh = (const short*)Wth + (long)(bn * 128 + srow) * WIDTH + scol;
    const long half = 64l * WIDTH;

    floatx4 acc[4][4] = {};
    const int r = lane & 15;
    const int kq = (lane >> 4) << 3;

    for (int kt = 0; kt < WIDTH; kt += 64) {
        __syncthreads();
        async_copy16(pAh + kt,             Ash0 + wv * 512);
        async_copy16(pAh + half + kt,      Ash0 + 2048 + wv * 512);
        async_copy16(pAh + kt + 32,        Ash1 + wv * 512);
        async_copy16(pAh + half + kt + 32, Ash1 + 2048 + wv * 512);
        async_copy16(pBh + kt,             Bsh0 + wv * 512);
        async_copy16(pBh + half + kt,      Bsh0 + 2048 + wv * 512);
        async_copy16(pBh + kt + 32,        Bsh1 + wv * 512);
        async_copy16(pBh + half + kt + 32, Bsh1 + 2048 + wv * 512);
        __syncthreads();
#pragma unroll
        for (int s = 0; s < 2; ++s) {
            const short* As = s ? Ash1 : Ash0;
            const short* Bs = s ? Bsh1 : Bsh0;
            short8 afh[4], bfh[4];
#pragma unroll
            for (int i = 0; i < 4; ++i)
                afh[i] = *reinterpret_cast<const short8*>(&As[(wm * 64 + i * 16 + r) * 32 + kq]);
#pragma unroll
            for (int j = 0; j < 4; ++j)
                bfh[j] = *reinterpret_cast<const short8*>(&Bs[(wn * 64 + j * 16 + r) * 32 + kq]);
#pragma unroll
            for (int i = 0; i < 4; ++i)
#pragma unroll
                for (int j = 0; j < 4; ++j)
                    acc[i][j] = __builtin_amdgcn_mfma_f32_16x16x32_bf16(afh[i], bfh[j], acc[i][j], 0, 0, 0);
        }
    }

    const int r4 = (lane >> 4) << 2;
#pragma unroll
    for (int i = 0; i < 4; ++i)
#pragma unroll
        for (int j = 0; j < 4; ++j) {
            const int col = bn * 128 + wn * 64 + j * 16 + r;
#pragma unroll
            for (int rr = 0; rr < 4; ++rr) {
                const int row = bm * 128 + wm * 64 + i * 16 + r4 + rr;
                float v = acc[i][j][rr];
                const unsigned brow = (unsigned)row / 7u;
                if (!(__bfloat162float(Y2h[(long)brow * WIDTH + col]) > 0.f)) v = 0.f;
                D2out[(long)row * WIDTH + col] = __float2bfloat16(v);
            }
        }
}

// ---------------- fused D3(+PD projection) + heady launch ----------------
// blocks x<nd: D3 with fused PD partial projection (bm=x fastest, bn=y);
// x>=nd && y==0: heady (Y3 projection, 3-pass); else idle.
__global__ __launch_bounds__(256) void d3heady_k(
    const __hip_bfloat16* __restrict__ D2,
    const __hip_bfloat16* __restrict__ Wth, const __hip_bfloat16* __restrict__ Wtl,
    const __hip_bfloat16* __restrict__ Y3h, const __hip_bfloat16* __restrict__ Y3l,
    const __hip_bfloat16* __restrict__ Wch, const __hip_bfloat16* __restrict__ Wcl,
    float* __restrict__ PDpart, float* __restrict__ PY,
    int nd, int Mrows)
{
    __shared__ __align__(16) short SM[26112];  // 52 KB
    const int tid = threadIdx.x;
    const int lane = tid & 63;
    const int wv = tid >> 6;
    const int r = lane & 15;
    const int kq = (lane >> 4) << 3;
    const int r4 = (lane >> 4) << 2;
    const int srow = tid >> 2;
    const int scol = (tid & 3) << 3;
    const long half = 64l * WIDTH;

    if ((int)blockIdx.x >= nd) {
        if (blockIdx.y != 0) return;
        // ---- heady body (3-pass Y3 @ Wcat^T) ----
        short* Ash = SM;          short* Asl = SM + 4096;
        short* Bsh = SM + 8192;   short* Bsl = SM + 9216;
        const int bm = blockIdx.x - nd;
        const short* pAh = (const short*)Y3h + (long)(bm * 128 + srow) * WIDTH + scol;
        const short* pAl = (const short*)Y3l + (long)(bm * 128 + srow) * WIDTH + scol;
        const long boff = (long)srow * WIDTH + scol;
        const short* pBh = (const short*)Wch;  const short* pBl = (const short*)Wcl;

        floatx4 acc[2][2] = {};
        for (int kt = 0; kt < WIDTH; kt += 32) {
            short8 gbh, gbl;
            if (tid < 128) {
                gbh = *reinterpret_cast<const short8*>(pBh + boff + kt);
                gbl = *reinterpret_cast<const short8*>(pBl + boff + kt);
            }
            __syncthreads();
            async_copy16(pAh + kt,        Ash + wv * 512);
            async_copy16(pAh + half + kt, Ash + 2048 + wv * 512);
            async_copy16(pAl + kt,        Asl + wv * 512);
            async_copy16(pAl + half + kt, Asl + 2048 + wv * 512);
            if (tid < 128) {
                *reinterpret_cast<short8*>(&Bsh[srow * 32 + scol]) = gbh;
                *reinterpret_cast<short8*>(&Bsl[srow * 32 + scol]) = gbl;
            }
            __syncthreads();
            short8 afh[2], afl[2], bfh[2], bfl[2];
#pragma unroll
            for (int i = 0; i < 2; ++i) {
                const int ar = (wv * 32 + i * 16 + r) * 32 + kq;
                afh[i] = *reinterpret_cast<const short8*>(&Ash[ar]);
                afl[i] = *reinterpret_cast<const short8*>(&Asl[ar]);
            }
#pragma unroll
            for (int j = 0; j < 2; ++j) {
                const int br = (j * 16 + r) * 32 + kq;
                bfh[j] = *reinterpret_cast<const short8*>(&Bsh[br]);
                bfl[j] = *reinterpret_cast<const short8*>(&Bsl[br]);
            }
#pragma unroll
            for (int i = 0; i < 2; ++i)
#pragma unroll
                for (int j = 0; j < 2; ++j) {
                    acc[i][j] = __builtin_amdgcn_mfma_f32_16x16x32_bf16(afh[i], bfh[j], acc[i][j], 0, 0, 0);
                    acc[i][j] = __builtin_amdgcn_mfma_f32_16x16x32_bf16(afh[i], bfl[j], acc[i][j], 0, 0, 0);
                    acc[i][j] = __builtin_amdgcn_mfma_f32_16x16x32_bf16(afl[i], bfh[j], acc[i][j], 0, 0, 0);
                }
        }
#pragma unroll
        for (int i = 0; i < 2; ++i)
#pragma unroll
            for (int j = 0; j < 2; ++j)
#pragma unroll
                for (int rr = 0; rr < 4; ++rr) {
                    const int row = bm * 128 + wv * 32 + i * 16 + r4 + rr;
                    PY[(long)row * 32 + j * 16 + r] = acc[i][j][rr];
                }
        return;
    }

    // ---- D3 body + fused PD projection ----
    short* Ash0 = SM;         short* Ash1 = SM + 4096;
    short* Bsh0 = SM + 8192;  short* Bsh1 = SM + 12288;
    short* T    = SM;            // 128 x 136
    short* WcH  = SM + 17408;    // 32 x 136
    short* WcL  = SM + 21760;    // 32 x 136

    const int wm = wv >> 1, wn = wv & 1;
    const int bm = blockIdx.x, bn = blockIdx.y;
    const short* pAh = (const short*)D2 + (long)(bm * 128 + srow) * WIDTH + scol;
    const short* pBh = (const short*)Wth + (long)(bn * 128 + srow) * WIDTH + scol;

    floatx4 acc[4][4] = {};
    for (int kt = 0; kt < WIDTH; kt += 64) {
        __syncthreads();
        async_copy16(pAh + kt,             Ash0 + wv * 512);
        async_copy16(pAh + half + kt,      Ash0 + 2048 + wv * 512);
        async_copy16(pAh + kt + 32,        Ash1 + wv * 512);
        async_copy16(pAh + half + kt + 32, Ash1 + 2048 + wv * 512);
        async_copy16(pBh + kt,             Bsh0 + wv * 512);
        async_copy16(pBh + half + kt,      Bsh0 + 2048 + wv * 512);
        async_copy16(pBh + kt + 32,        Bsh1 + wv * 512);
        async_copy16(pBh + half + kt + 32, Bsh1 + 2048 + wv * 512);
        __syncthreads();
#pragma unroll
        for (int s = 0; s < 2; ++s) {
            const short* As = s ? Ash1 : Ash0;
            const short* Bs = s ? Bsh1 : Bsh0;
            short8 afh[4], bfh[4];
#pragma unroll
            for (int i = 0; i < 4; ++i)
                afh[i] = *reinterpret_cast<const short8*>(&As[(wm * 64 + i * 16 + r) * 32 + kq]);
#pragma unroll
            for (int j = 0; j < 4; ++j)
                bfh[j] = *reinterpret_cast<const short8*>(&Bs[(wn * 64 + j * 16 + r) * 32 + kq]);
#pragma unroll
            for (int i = 0; i < 4; ++i)
#pragma unroll
                for (int j = 0; j < 4; ++j)
                    acc[i][j] = __builtin_amdgcn_mfma_f32_16x16x32_bf16(afh[i], bfh[j], acc[i][j], 0, 0, 0);
        }
    }

    __syncthreads();
#pragma unroll
    for (int i = 0; i < 4; ++i)
#pragma unroll
        for (int j = 0; j < 4; ++j) {
            const int coll = wn * 64 + j * 16 + r;
            const int colg = bn * 128 + coll;
#pragma unroll
            for (int rr = 0; rr < 4; ++rr) {
                const int rowl = wm * 64 + i * 16 + r4 + rr;
                const int rowg = bm * 128 + rowl;
                float v = acc[i][j][rr];
                const unsigned brow = (unsigned)rowg / 7u;
                if (!(__bfloat162float(Y3h[(long)brow * WIDTH + colg]) > 0.f)) v = 0.f;
                __hip_bfloat16 hb = __float2bfloat16(v);
                T[rowl * 136 + coll] = *reinterpret_cast<short*>(&hb);
            }
        }
    {
        const int n = tid >> 4, k8 = (tid & 15) * 8;
        const short* wh = (const short*)Wch;
        const short* wl = (const short*)Wcl;
        *reinterpret_cast<short8*>(&WcH[n * 136 + k8]) =
            *reinterpret_cast<const short8*>(wh + n * WIDTH + bn * 128 + k8);
        *reinterpret_cast<short8*>(&WcH[(n + 16) * 136 + k8]) =
            *reinterpret_cast<const short8*>(wh + (n + 16) * WIDTH + bn * 128 + k8);
        *reinterpret_cast<short8*>(&WcL[n * 136 + k8]) =
            *reinterpret_cast<const short8*>(wl + n * WIDTH + bn * 128 + k8);
        *reinterpret_cast<short8*>(&WcL[(n + 16) * 136 + k8]) =
            *reinterpret_cast<const short8*>(wl + (n + 16) * WIDTH + bn * 128 + k8);
    }
    __syncthreads();

    floatx4 accp[2][2] = {};
#pragma unroll
    for (int kk = 0; kk < 128; kk += 32) {
        short8 af[2], bh8[2], bl8[2];
#pragma unroll
        for (int i = 0; i < 2; ++i)
            af[i] = *reinterpret_cast<const short8*>(&T[(wv * 32 + i * 16 + r) * 136 + kk + kq]);
#pragma unroll
        for (int j = 0; j < 2; ++j) {
            bh8[j] = *reinterpret_cast<const short8*>(&WcH[(j * 16 + r) * 136 + kk + kq]);
            bl8[j] = *reinterpret_cast<const short8*>(&WcL[(j * 16 + r) * 136 + kk + kq]);
        }
#pragma unroll
        for (int i = 0; i < 2; ++i)
#pragma unroll
            for (int j = 0; j < 2; ++j) {
                accp[i][j] = __builtin_amdgcn_mfma_f32_16x16x32_bf16(af[i], bh8[j], accp[i][j], 0, 0, 0);
                accp[i][j] = __builtin_amdgcn_mfma_f32_16x16x32_bf16(af[i], bl8[j], accp[i][j], 0, 0, 0);
            }
    }
#pragma unroll
    for (int i = 0; i < 2; ++i)
#pragma unroll
        for (int j = 0; j < 2; ++j)
#pragma unroll
            for (int rr = 0; rr < 4; ++rr) {
                const int rowg = bm * 128 + wv * 32 + i * 16 + r4 + rr;
                PDpart[((long)bn * Mrows + rowg) * 32 + j * 16 + r] = accp[i][j][rr];
            }
}

// ---------------- finalize: 7x7 algebra; reduces PDpart inline ----------------
__device__ __forceinline__ int midx(int rr, int cc) {
    const int i = rr - cc;
    return i * 7 - (i * (i - 1)) / 2 + cc;
}

__global__ __launch_bounds__(64) void finalize_k(
    const float* __restrict__ PY,
    const float* __restrict__ PDpart,   // [8][Mrows][32]
    const float* __restrict__ vel_g,
    const float* __restrict__ acc_g,
    const float* __restrict__ b_ld,
    const float* __restrict__ b_lo,
    float* __restrict__ out,
    int b0, int Mrows)
{
    __shared__ float lval[28];
    __shared__ int gpv[7];
    __shared__ float derl[29 * 7];
    __shared__ float Lm[49], Mm[49], dLt[49], uu[49];
    __shared__ float wvv[7], pv[7], Cv[7], Gv[7], tauv[7], vl[7], ac[7];

    const int bl = blockIdx.x, tid = threadIdx.x;
    const int b = b0 + bl;
    if (tid < 28) {
        float s = PY[(long)bl * 32 + tid];
        if (tid < 7) {
            s += b_ld[tid];
            gpv[tid] = s > 0.f;
            lval[tid] = s > 0.f ? s : 0.f;
        } else {
            lval[tid] = s + b_lo[tid - 7];
        }
    }
    if (tid >= 28 && tid < 35) {
        vl[tid - 28] = vel_g[b * 7 + tid - 28];
        ac[tid - 28] = acc_g[b * 7 + tid - 28];
    }
    __syncthreads();
    for (int idx = tid; idx < 203; idx += 64) {
        const int m = idx / 7, d = idx % 7;
        float v = 0.f;
#pragma unroll
        for (int p = 0; p < 8; ++p)
            v += PDpart[((long)p * Mrows + bl * 7 + d) * 32 + m];
        if (m < 7 && !gpv[m]) v = 0.f;
        derl[m * 7 + d] = v;
    }
    __syncthreads();
    if (tid < 49) {
        const int rr = tid / 7, cc = tid % 7;
        Lm[tid] = (rr >= cc) ? lval[midx(rr, cc)] : 0.f;
    }
    __syncthreads();
    if (tid < 49) {
        const int rr = tid / 7, cc = tid % 7;
        float s = 0.f;
        for (int k = 0; k < 7; ++k) s += Lm[rr * 7 + k] * Lm[cc * 7 + k];
        if (rr == cc) s += 1e-5f;
        Mm[tid] = s;
        float t = 0.f;
        if (rr >= cc) {
            const int m = midx(rr, cc);
            for (int d = 0; d < 7; ++d) t += derl[m * 7 + d] * vl[d];
        }
        dLt[tid] = t;
        float u = 0.f;
        for (int r2 = cc; r2 < 7; ++r2) u += vl[r2] * derl[midx(r2, cc) * 7 + rr];
        uu[tid] = u;
    } else if (tid >= 49 && tid < 56) {
        const int j = tid - 49;
        float s = 0.f;
        for (int r2 = 0; r2 < 7; ++r2) s += Lm[r2 * 7 + j] * vl[r2];
        wvv[j] = s;
    }
    __syncthreads();
    if (tid < 7) {
        float s = 0.f;
        for (int r2 = 0; r2 < 7; ++r2) s += dLt[r2 * 7 + tid] * vl[r2];
        pv[tid] = s;
    }
    __syncthreads();
    if (tid < 7) {
        float s = 0.f, q = 0.f, md = 0.f;
        for (int c = 0; c < 7; ++c) {
            s += Lm[tid * 7 + c] * pv[c] + dLt[tid * 7 + c] * wvv[c];
            q += uu[tid * 7 + c] * wvv[c];
            md += Mm[tid * 7 + c] * ac[c];
        }
        Cv[tid] = s - q;
        Gv[tid] = derl[28 * 7 + tid];
        tauv[tid] = md + Cv[tid] + Gv[tid];
    }
    __syncthreads();
    if (tid < 49) out[57344 + (long)b * 49 + tid] = Mm[tid];
    if (tid < 7) {
        out[(long)b * 7 + tid] = tauv[tid];
        out[458752 + (long)b * 7 + tid] = Cv[tid];
        out[516096 + (long)b * 7 + tid] = Gv[tid];
    }
}

extern "C" void kernel_launch(void* const* d_in, const int* in_sizes, int n_in,
                              void* d_out, int out_size, void* d_ws, size_t ws_size,
                              hipStream_t stream)
{
    const float* state = (const float*)d_in[0];
    const float* vel   = (const float*)d_in[1];
    const float* accel = (const float*)d_in[2];
    const float* W_in  = (const float*)d_in[3];
    const float* b_in  = (const float*)d_in[4];
    const float* W_h   = (const float*)d_in[5];
    const float* b_h   = (const float*)d_in[6];
    const float* W_g   = (const float*)d_in[7];
    /* d_in[8] = b_g unused */
    const float* W_ld  = (const float*)d_in[9];
    const float* b_ld  = (const float*)d_in[10];
    const float* W_lo  = (const float*)d_in[11];
    const float* b_lo  = (const float*)d_in[12];
    float* outp = (float*)d_out;

    char* ws = (char*)d_ws;
    __hip_bfloat16* Wth = (__hip_bfloat16*)ws; ws += (size_t)WIDTH * WIDTH * 2;
    __hip_bfloat16* Wtl = (__hip_bfloat16*)ws; ws += (size_t)WIDTH * WIDTH * 2;
    __hip_bfloat16* Wch = (__hip_bfloat16*)ws; ws += 32 * WIDTH * 2;
    __hip_bfloat16* Wcl = (__hip_bfloat16*)ws; ws += 32 * WIDTH * 2;
    const size_t fixed = (size_t)(ws - (char*)d_ws);

    // per-sample: Y 4*2048 + D1 14336 + D2 14336 + PY 128 = 37120 B
    int CH = 128;
    for (int cand = 8192; cand >= 128; cand >>= 1) {
        size_t need = fixed + (size_t)cand * 37120;
        if (need <= ws_size) { CH = cand; break; }
    }
    const int NCH = BATCH / CH;

    const size_t YB = (size_t)CH * WIDTH * 2;
    const size_t DB = (size_t)CH * 7 * WIDTH * 2;
    __hip_bfloat16* Yah = (__hip_bfloat16*)ws; ws += YB;   // Y1 -> Y3
    __hip_bfloat16* Yal = (__hip_bfloat16*)ws; ws += YB;
    __hip_bfloat16* Ybh = (__hip_bfloat16*)ws; ws += YB;   // Y2
    __hip_bfloat16* Ybl = (__hip_bfloat16*)ws; ws += YB;
    __hip_bfloat16* Dah = (__hip_bfloat16*)ws; ws += DB;   // D1 (aliased as PDpart in D3 phase)
    __hip_bfloat16* Dbh = (__hip_bfloat16*)ws; ws += DB;   // D2
    float* PY = (float*)ws; ws += (size_t)CH * 32 * 4;
    float* PDpart = (float*)Dah;   // 8*(7*CH)*32*4 = CH*7168 B <= DB

    const int Mrows = CH * 7;
    const int nd = Mrows / 128;
    const int ny = CH / 128;

    transpose_k<<<dim3(32, 32), dim3(256), 0, stream>>>(W_h, Wth, Wtl);
    buildwcat_k<<<dim3(128), dim3(256), 0, stream>>>(W_ld, W_lo, W_g, Wch, Wcl);

    for (int c = 0; c < NCH; ++c) {
        prep_k<<<dim3(CH), dim3(256), 0, stream>>>(state + (size_t)c * CH * 7, W_in, b_in,
                                                   Yah, Yal, Dah);
        gemm_y<<<dim3(ny, 8), dim3(256), 0, stream>>>(
            Yah, Yal, Wth, Wtl, b_h, Ybh, Ybl);                                // Y2
        d2y3_k<<<dim3(nd + ny, 8), dim3(256), 0, stream>>>(
            Dah, Wth, Wtl, Ybh, Ybl, b_h, Dbh, Yah, Yal, nd);                  // D2 + Y3
        d3heady_k<<<dim3(nd + ny, 8), dim3(256), 0, stream>>>(
            Dbh, Wth, Wtl, Yah, Yal, Wch, Wcl, PDpart, PY, nd, Mrows);         // D3+PD + heady
        finalize_k<<<dim3(CH), dim3(64), 0, stream>>>(PY, PDpart, vel, accel, b_ld, b_lo,
                                                      outp, c * CH, Mrows);
    }
    (void)in_sizes; (void)n_in; (void)out_size;
}